// Round 3
// baseline (497.387 us; speedup 1.0000x reference)
//
#include <hip/hip_runtime.h>
#include <hip/hip_bf16.h>

// x[32768,256] f32, W[256,256], b[256], emb[1024,256]
// d_out: quant[32768*256] | indices[32768] (as float) | loss[1]
//
// Pipeline:
//   k_ee      : ee[n] = sum emb[n]^2
//   k_proj    : z = x @ W^T + b (exact fp32, written into quant region)
//   k_screen  : bf16 MFMA distance GEMM -> argmin + 2nd-best gap.
//               Writes idx (+4096 flag if gap < B_S) to indices slot.
//   k_rescore : exact fp32 re-argmin for flagged tokens (same formula that
//               passed round 2: u = fl(zz+ee[n]); s = fma(-2,dot,u)).
//   k_gather  : quant = emb[idx] (in-place over z), loss partials
//   k_loss    : 1.25 * sum / (T*D)
//
// Safety: reference dists are quantized to ulp(~256)=3.05e-5; approx dot error
// rms ~1.4e-5; B_S = 5e-4 >= 2*ulp + 4*(8 sigma) -> unflagged tokens have a
// guaranteed-unique exact argmin. zz order differences are lattice-exact.
#define TT 32768
#define DD 256
#define KK 1024
#define B_S 5e-4f

typedef __attribute__((ext_vector_type(8)))  short bf16x8;
typedef __attribute__((ext_vector_type(4)))  short bf16x4s;
typedef __attribute__((ext_vector_type(16))) float f32x16;

static inline __device__ short f2bf(float v) {
    __hip_bfloat16 h = __float2bfloat16(v);
    return __builtin_bit_cast(short, h);
}

// ---------------------------------------------------------------------------
__global__ void k_ee(const float* __restrict__ emb, float* __restrict__ ee) {
    int n = blockIdx.x * 256 + threadIdx.x;
    if (n >= KK) return;
    const float4* r = (const float4*)(emb + (size_t)n * DD);
    float s = 0.f;
#pragma unroll
    for (int i = 0; i < DD / 4; ++i) {
        float4 v = r[i];
        s += v.x * v.x + v.y * v.y + v.z * v.z + v.w * v.w;
    }
    ee[n] = s;
}

// ---------------------------------------------------------------------------
// z = x @ W^T + b. 64 tokens/block, 256 outs, grid 512 (2 blocks/CU).
__launch_bounds__(256, 2)
__global__ void k_proj(const float* __restrict__ x, const float* __restrict__ W,
                       const float* __restrict__ bias, float* __restrict__ z) {
    __shared__ float As[32][68];
    __shared__ float Bs[32][264];
    const int tid = threadIdx.x;
    const int tx = tid & 31;       // col groups: cols tx*4..+3 and 128+tx*4..+3
    const int ty = tid >> 5;       // row group: 8 tokens
    const int t0 = blockIdx.x * 64;

    float acc[8][8];
#pragma unroll
    for (int i = 0; i < 8; ++i)
#pragma unroll
        for (int j = 0; j < 8; ++j) acc[i][j] = 0.f;

    for (int kb = 0; kb < DD; kb += 32) {
        __syncthreads();
#pragma unroll
        for (int j = 0; j < 2; ++j) {           // A: 64x32
            int idx = j * 256 + tid;
            int row = idx >> 3, c4 = idx & 7;
            float4 v = *(const float4*)(x + (size_t)(t0 + row) * DD + kb + c4 * 4);
            As[c4 * 4 + 0][row] = v.x; As[c4 * 4 + 1][row] = v.y;
            As[c4 * 4 + 2][row] = v.z; As[c4 * 4 + 3][row] = v.w;
        }
#pragma unroll
        for (int j = 0; j < 8; ++j) {           // B: 256x32 (W rows)
            int idx = j * 256 + tid;
            int o = idx >> 3, c4 = idx & 7;
            float4 v = *(const float4*)(W + (size_t)o * DD + kb + c4 * 4);
            Bs[c4 * 4 + 0][o] = v.x; Bs[c4 * 4 + 1][o] = v.y;
            Bs[c4 * 4 + 2][o] = v.z; Bs[c4 * 4 + 3][o] = v.w;
        }
        __syncthreads();
#pragma unroll 8
        for (int kk = 0; kk < 32; ++kk) {
            float4 a0 = *(const float4*)&As[kk][ty * 8];
            float4 a1 = *(const float4*)&As[kk][ty * 8 + 4];
            float4 b0 = *(const float4*)&Bs[kk][tx * 4];        // conflict-free
            float4 b1 = *(const float4*)&Bs[kk][128 + tx * 4];
            float av[8] = {a0.x, a0.y, a0.z, a0.w, a1.x, a1.y, a1.z, a1.w};
            float bv[8] = {b0.x, b0.y, b0.z, b0.w, b1.x, b1.y, b1.z, b1.w};
#pragma unroll
            for (int i = 0; i < 8; ++i)
#pragma unroll
                for (int j = 0; j < 8; ++j)
                    acc[i][j] = fmaf(av[i], bv[j], acc[i][j]);
        }
    }
    float bi0[4], bi1[4];
#pragma unroll
    for (int j = 0; j < 4; ++j) { bi0[j] = bias[tx * 4 + j]; bi1[j] = bias[128 + tx * 4 + j]; }
#pragma unroll
    for (int i = 0; i < 8; ++i) {
        int t = t0 + ty * 8 + i;
        float4 o0 = {acc[i][0] + bi0[0], acc[i][1] + bi0[1], acc[i][2] + bi0[2], acc[i][3] + bi0[3]};
        float4 o1 = {acc[i][4] + bi1[0], acc[i][5] + bi1[1], acc[i][6] + bi1[2], acc[i][7] + bi1[3]};
        *(float4*)(z + (size_t)t * DD + tx * 4)       = o0;
        *(float4*)(z + (size_t)t * DD + 128 + tx * 4) = o1;
    }
}

// ---------------------------------------------------------------------------
// bf16 MFMA screening. 64 tokens/block, all 1024 codes, grid 512.
#define SW 264   // A_s row stride (bf16 elems); 528 B, mult of 16, 33 mod 8 = 1
#define BW 40    // B_s row stride (bf16 elems); 80 B

__launch_bounds__(256, 2)
__global__ void k_screen(const float* __restrict__ z, const float* __restrict__ emb,
                         const float* __restrict__ ee_g, float* __restrict__ out_idx) {
    __shared__ __align__(16) short A_s[64 * SW];
    __shared__ __align__(16) short B_s[128 * BW];
    __shared__ float ee_s[1024];
    __shared__ float zzs[64];
    __shared__ float r_bv[64]; __shared__ int r_bi[64]; __shared__ float r_sv[64];

    const int tid = threadIdx.x;
    const int w = tid >> 6, lane = tid & 63;
    const int l31 = lane & 31, h = lane >> 5;
    const int t0 = blockIdx.x * 64;
    const int wr = (w >> 1) * 32, wc = (w & 1) * 64;

#pragma unroll
    for (int i = 0; i < 4; ++i) ee_s[i * 256 + tid] = ee_g[i * 256 + tid];

    // A init: z tile -> bf16 LDS (full K=256 resident) + zz row sums
#pragma unroll
    for (int i = 0; i < 16; ++i) {
        int tl = i * 4 + w;
        float4 v = *(const float4*)(z + (size_t)(t0 + tl) * DD + lane * 4);
        float sq = v.x * v.x + v.y * v.y + v.z * v.z + v.w * v.w;
#pragma unroll
        for (int o = 32; o; o >>= 1) sq += __shfl_xor(sq, o);
        if (lane == 0) zzs[tl] = sq;
        bf16x4s hb = {f2bf(v.x), f2bf(v.y), f2bf(v.z), f2bf(v.w)};
        *(bf16x4s*)&A_s[tl * SW + lane * 4] = hb;
    }

    float bestv[16], secv[16]; int besti[16];
#pragma unroll
    for (int r = 0; r < 16; ++r) { bestv[r] = 1e30f; secv[r] = 1e30f; besti[r] = 0; }

    // B tile prefetch registers
    float4 pre[4];
    {
        int nc = 0, kbi = 0;
#pragma unroll
        for (int r = 0; r < 4; ++r) {
            int f = r * 256 + tid, n_loc = f >> 3, c = f & 7;
            pre[r] = *(const float4*)(emb + (size_t)(nc * 128 + n_loc) * DD + kbi * 32 + c * 4);
        }
    }
    __syncthreads();   // A_s, zzs, ee_s ready

    for (int nc = 0; nc < 8; ++nc) {
        f32x16 acc0, acc1;
#pragma unroll
        for (int r = 0; r < 16; ++r) { acc0[r] = 0.f; acc1[r] = 0.f; }

        for (int kbi = 0; kbi < 8; ++kbi) {
            __syncthreads();
#pragma unroll
            for (int r = 0; r < 4; ++r) {       // write staged B tile
                int f = r * 256 + tid, n_loc = f >> 3, c = f & 7;
                float4 v = pre[r];
                bf16x4s hb = {f2bf(v.x), f2bf(v.y), f2bf(v.z), f2bf(v.w)};
                *(bf16x4s*)&B_s[n_loc * BW + c * 4] = hb;
            }
            __syncthreads();
            {   // prefetch next tile
                int rr = nc * 8 + kbi; int nrr = rr < 63 ? rr + 1 : 63;
                int nnc = nrr >> 3, nkbi = nrr & 7;
#pragma unroll
                for (int r = 0; r < 4; ++r) {
                    int f = r * 256 + tid, n_loc = f >> 3, c = f & 7;
                    pre[r] = *(const float4*)(emb + (size_t)(nnc * 128 + n_loc) * DD + nkbi * 32 + c * 4);
                }
            }
#pragma unroll
            for (int ks = 0; ks < 2; ++ks) {
                bf16x8 a  = *(bf16x8*)&A_s[(wr + l31) * SW + kbi * 32 + ks * 16 + h * 8];
                bf16x8 b0 = *(bf16x8*)&B_s[(wc + l31) * BW + ks * 16 + h * 8];
                bf16x8 b1 = *(bf16x8*)&B_s[(wc + 32 + l31) * BW + ks * 16 + h * 8];
                acc0 = __builtin_amdgcn_mfma_f32_32x32x16_bf16(a, b0, acc0, 0, 0, 0);
                acc1 = __builtin_amdgcn_mfma_f32_32x32x16_bf16(a, b1, acc1, 0, 0, 0);
            }
        }
        // fold: s = fl(fl(zz+ee) - 2*dot) ; ascending n within lane (j=0 then 1)
#pragma unroll
        for (int j = 0; j < 2; ++j) {
            int n = nc * 128 + wc + j * 32 + l31;
            float en = ee_s[n];
#pragma unroll
            for (int r = 0; r < 16; ++r) {
                int row = (r & 3) + 8 * (r >> 2) + 4 * h;
                float u = zzs[wr + row] + en;
                float d = (j == 0) ? acc0[r] : acc1[r];
                float s = fmaf(-2.f, d, u);
                if (s < bestv[r])      { secv[r] = bestv[r]; bestv[r] = s; besti[r] = n; }
                else if (s < secv[r])  { secv[r] = s; }
            }
        }
    }

    // cross-lane reduce within each 32-lane half (cols)
#pragma unroll
    for (int o = 1; o < 32; o <<= 1) {
#pragma unroll
        for (int r = 0; r < 16; ++r) {
            float ov = __shfl_xor(bestv[r], o);
            int   oi = __shfl_xor(besti[r], o);
            float os = __shfl_xor(secv[r], o);
            float mx = fmaxf(bestv[r], ov);
            secv[r] = fminf(fminf(secv[r], os), mx);
            if (ov < bestv[r] || (ov == bestv[r] && oi < besti[r])) { bestv[r] = ov; besti[r] = oi; }
        }
    }
    // combine the two col-parity waves per row block via LDS
    if ((w & 1) == 0 && l31 == 0) {
#pragma unroll
        for (int r = 0; r < 16; ++r) {
            int tr = wr + (r & 3) + 8 * (r >> 2) + 4 * h;
            r_bv[tr] = bestv[r]; r_bi[tr] = besti[r]; r_sv[tr] = secv[r];
        }
    }
    __syncthreads();
    if ((w & 1) == 1 && l31 == 0) {
#pragma unroll
        for (int r = 0; r < 16; ++r) {
            int tr = wr + (r & 3) + 8 * (r >> 2) + 4 * h;
            float lv = r_bv[tr]; int li = r_bi[tr]; float ls = r_sv[tr];
            float mx = fmaxf(lv, bestv[r]);
            float ns = fminf(fminf(ls, secv[r]), mx);
            float nv; int ni;
            if (bestv[r] < lv || (bestv[r] == lv && besti[r] < li)) { nv = bestv[r]; ni = besti[r]; }
            else { nv = lv; ni = li; }
            r_bv[tr] = nv; r_bi[tr] = ni; r_sv[tr] = ns;
        }
    }
    __syncthreads();
    if (tid < 64) {
        float bv = r_bv[tid], sv = r_sv[tid];
        int bi = r_bi[tid];
        float flag = ((sv - bv) < B_S) ? 4096.0f : 0.0f;
        out_idx[t0 + tid] = (float)bi + flag;
    }
}

// ---------------------------------------------------------------------------
// Exact fp32 re-argmin for flagged tokens. grid 512 (one block per 64 tokens).
__launch_bounds__(256, 2)
__global__ void k_rescore(const float* __restrict__ z, const float* __restrict__ emb,
                          const float* __restrict__ ee_g, float* __restrict__ out_idx) {
    __shared__ float zrow[4][256];
    __shared__ float zz4[4];
    __shared__ int list[64];
    __shared__ int nflag;
    __shared__ float redv[4]; __shared__ int redi[4];
    const int tid = threadIdx.x;
    const int w = tid >> 6, lane = tid & 63;
    const int t0 = blockIdx.x * 64;

    if (tid == 0) nflag = 0;
    __syncthreads();
    if (tid < 64) {
        float v = out_idx[t0 + tid];
        if (v >= 4096.0f) { int p = atomicAdd(&nflag, 1); list[p] = tid; }
    }
    __syncthreads();
    const int cnt = nflag;

    for (int base = 0; base < cnt; base += 4) {
        int nt = min(4, cnt - base);
        for (int q = 0; q < nt; ++q) {
            int t = t0 + list[base + q];
            zrow[q][tid] = z[(size_t)t * DD + tid];
        }
        __syncthreads();
        if (w < nt) {       // wave w computes zz for token w
            float s = 0.f;
#pragma unroll
            for (int k = 0; k < 4; ++k) { float v = zrow[w][lane + 64 * k]; s += v * v; }
#pragma unroll
            for (int o = 32; o; o >>= 1) s += __shfl_xor(s, o);
            if (lane == 0) zz4[w] = s;
        }
        __syncthreads();

        float bv[4] = {1e30f, 1e30f, 1e30f, 1e30f};
        int   bi[4] = {0, 0, 0, 0};
        for (int c = 0; c < 4; ++c) {
            int n = c * 256 + tid;
            float en = ee_g[n];
            float d0 = 0.f, d1 = 0.f, d2 = 0.f, d3 = 0.f;
            const float4* er = (const float4*)(emb + (size_t)n * DD);
#pragma unroll 8
            for (int k = 0; k < 64; ++k) {
                float4 e = er[k];
                d0 = fmaf(e.x, zrow[0][k * 4 + 0], d0); d0 = fmaf(e.y, zrow[0][k * 4 + 1], d0);
                d0 = fmaf(e.z, zrow[0][k * 4 + 2], d0); d0 = fmaf(e.w, zrow[0][k * 4 + 3], d0);
                d1 = fmaf(e.x, zrow[1][k * 4 + 0], d1); d1 = fmaf(e.y, zrow[1][k * 4 + 1], d1);
                d1 = fmaf(e.z, zrow[1][k * 4 + 2], d1); d1 = fmaf(e.w, zrow[1][k * 4 + 3], d1);
                d2 = fmaf(e.x, zrow[2][k * 4 + 0], d2); d2 = fmaf(e.y, zrow[2][k * 4 + 1], d2);
                d2 = fmaf(e.z, zrow[2][k * 4 + 2], d2); d2 = fmaf(e.w, zrow[2][k * 4 + 3], d2);
                d3 = fmaf(e.x, zrow[3][k * 4 + 0], d3); d3 = fmaf(e.y, zrow[3][k * 4 + 1], d3);
                d3 = fmaf(e.z, zrow[3][k * 4 + 2], d3); d3 = fmaf(e.w, zrow[3][k * 4 + 3], d3);
            }
            float dd[4] = {d0, d1, d2, d3};
#pragma unroll
            for (int q = 0; q < 4; ++q) {
                float u = zz4[q] + en;
                float s = fmaf(-2.f, dd[q], u);
                if (s < bv[q]) { bv[q] = s; bi[q] = n; }
            }
        }
        for (int q = 0; q < nt; ++q) {
            float v = bv[q]; int i = bi[q];
#pragma unroll
            for (int o = 1; o < 64; o <<= 1) {
                float ov = __shfl_xor(v, o); int oi = __shfl_xor(i, o);
                if (ov < v || (ov == v && oi < i)) { v = ov; i = oi; }
            }
            if (lane == 0) { redv[w] = v; redi[w] = i; }
            __syncthreads();
            if (tid == 0) {
                float fv = redv[0]; int fi = redi[0];
#pragma unroll
                for (int ww = 1; ww < 4; ++ww) {
                    if (redv[ww] < fv || (redv[ww] == fv && redi[ww] < fi)) { fv = redv[ww]; fi = redi[ww]; }
                }
                out_idx[t0 + list[base + q]] = (float)fi;
            }
            __syncthreads();
        }
    }
}

// ---------------------------------------------------------------------------
// quant = emb[idx] (in-place over z), loss partials. 128 tokens/block, grid 256.
__global__ void k_gather(float* __restrict__ zq, const float* __restrict__ emb,
                         const float* __restrict__ out_idx, float* __restrict__ partial) {
    __shared__ float red[4];
    const int tid = threadIdx.x;
    const int t0 = blockIdx.x * 128;
    const int tl = tid >> 1, part = tid & 1;
    int widx = (int)out_idx[t0 + tl];
    widx = min(max(widx, 0), KK - 1);
    const float* erow = emb + (size_t)widx * DD;
    float* qrow = zq + (size_t)(t0 + tl) * DD;
    float lsum = 0.f;
#pragma unroll
    for (int k = 0; k < 32; ++k) {
        int f = part + 2 * k;
        float4 e  = *(const float4*)(erow + f * 4);
        float4 zv = *(const float4*)(qrow + f * 4);
        float dx = e.x - zv.x, dy = e.y - zv.y, dz = e.z - zv.z, dw = e.w - zv.w;
        lsum += dx * dx + dy * dy + dz * dz + dw * dw;
        *(float4*)(qrow + f * 4) = e;
    }
#pragma unroll
    for (int off = 32; off; off >>= 1) lsum += __shfl_down(lsum, off);
    if ((tid & 63) == 0) red[tid >> 6] = lsum;
    __syncthreads();
    if (tid == 0) partial[blockIdx.x] = red[0] + red[1] + red[2] + red[3];
}

// ---------------------------------------------------------------------------
__global__ void k_loss(const float* __restrict__ partial, float* __restrict__ out_loss) {
    __shared__ float red[4];
    int tid = threadIdx.x;
    float s = partial[tid];
#pragma unroll
    for (int off = 32; off; off >>= 1) s += __shfl_down(s, off);
    if ((tid & 63) == 0) red[tid >> 6] = s;
    __syncthreads();
    if (tid == 0)
        out_loss[0] = (red[0] + red[1] + red[2] + red[3]) * (1.25f / 8388608.0f);
}

// ---------------------------------------------------------------------------
extern "C" void kernel_launch(void* const* d_in, const int* in_sizes, int n_in,
                              void* d_out, int out_size, void* d_ws, size_t ws_size,
                              hipStream_t stream) {
    const float* x   = (const float*)d_in[0];
    const float* W   = (const float*)d_in[1];
    const float* b   = (const float*)d_in[2];
    const float* emb = (const float*)d_in[3];

    float* out   = (float*)d_out;
    float* quant = out;                          // holds z, then quant
    float* oidx  = out + (size_t)TT * DD;
    float* oloss = oidx + TT;

    float* ee      = (float*)d_ws;               // 1024 f
    float* partial = ee + KK;                    // 256 f

    k_ee     <<<KK / 256, 256, 0, stream>>>(emb, ee);
    k_proj   <<<TT / 64,  256, 0, stream>>>(x, W, b, quant);
    k_screen <<<TT / 64,  256, 0, stream>>>(quant, emb, ee, oidx);
    k_rescore<<<TT / 64,  256, 0, stream>>>(quant, emb, ee, oidx);
    k_gather <<<TT / 128, 256, 0, stream>>>(quant, emb, oidx, partial);
    k_loss   <<<1,        256, 0, stream>>>(partial, oloss);
}

// Round 6
// 379.438 us; speedup vs baseline: 1.3109x; 1.3109x over previous
//
#include <hip/hip_runtime.h>
#include <hip/hip_bf16.h>

// x[32768,256] f32, W[256,256], b[256], emb[1024,256]
// d_out: quant[32768*256] | indices[32768] (as float) | loss[1]
//
// Pipeline:
//   k_ee      : ee[n] = sum emb[n]^2
//   k_proj    : z = x @ W^T + b via 3-way-split bf16 MFMA (err ~3e-7)
//   k_screen  : bf16 MFMA distance screen -> idx (+4096 flag if top-2 gap
//               < B_S). EXACT round-3 code (harness-proven incl. replays).
//   k_rescore : exact fp32 full re-argmin for flagged tokens. Deterministic
//               ballot-built list, batched 8 tokens, no atomics.
//   k_gather  : quant = emb[idx] (in-place over z), loss partials
//   k_loss    : 1.25 * sum / (T*D)
//
// Numerics: reference dist = fl(fl(zz+ee[n]) - 2*dot) quantized to ulp(~256)
// ~3e-5. Screen score error sigma ~2.7e-5; B_S = 5e-4 >> 8*sigma + 2 ulp, so
// unflagged tokens have a guaranteed-unique exact argmin; flagged tokens get
// the full exact scan (u = fl(zz+ee[n]); s = fma(-2,dot,u); ascending-n
// first-min ties) — the round-2/3 validated formula.
#define TT 32768
#define DD 256
#define KK 1024
#define B_S 5e-4f

typedef __attribute__((ext_vector_type(8)))  short bf16x8;
typedef __attribute__((ext_vector_type(4)))  short bf16x4s;
typedef __attribute__((ext_vector_type(16))) float f32x16;

static inline __device__ short f2bf(float v) {
    __hip_bfloat16 h = __float2bfloat16(v);
    return __builtin_bit_cast(short, h);
}
static inline __device__ float bf2f(short s) {
    __hip_bfloat16 h = __builtin_bit_cast(__hip_bfloat16, s);
    return __bfloat162float(h);
}

// ---------------------------------------------------------------------------
__global__ void k_ee(const float* __restrict__ emb, float* __restrict__ ee) {
    int n = blockIdx.x * 256 + threadIdx.x;
    if (n >= KK) return;
    const float4* r = (const float4*)(emb + (size_t)n * DD);
    float s = 0.f;
#pragma unroll
    for (int i = 0; i < DD / 4; ++i) {
        float4 v = r[i];
        s += v.x * v.x + v.y * v.y + v.z * v.z + v.w * v.w;
    }
    ee[n] = s;
}

// ---------------------------------------------------------------------------
// z = x @ W^T + b via 3-way split bf16 MFMA. 64 tokens x 256 outs per block.
#define PW 40   // bf16 row stride for 32-k tiles (80 B: 16B-aligned)

__launch_bounds__(256, 2)
__global__ void k_proj(const float* __restrict__ x, const float* __restrict__ W,
                       const float* __restrict__ bias, float* __restrict__ z) {
    __shared__ __align__(16) short Ax[3][64 * PW];    // 15 KB
    __shared__ __align__(16) short Bw[3][256 * PW];   // 60 KB
    const int tid = threadIdx.x;
    const int w = tid >> 6, lane = tid & 63;
    const int l31 = lane & 31, h = lane >> 5;
    const int t0 = blockIdx.x * 64;
    const int wt = (w & 1) * 32;        // wave token offset
    const int wc = (w >> 1) * 128;      // wave col offset

    f32x16 acc[4];
#pragma unroll
    for (int cb = 0; cb < 4; ++cb)
#pragma unroll
        for (int r = 0; r < 16; ++r) acc[cb][r] = 0.f;

    for (int kb = 0; kb < DD; kb += 32) {
        __syncthreads();
        // x tile 64x32 -> 3-way split
#pragma unroll
        for (int j = 0; j < 2; ++j) {
            int idx = j * 256 + tid, row = idx >> 3, c4 = idx & 7;
            float4 v = *(const float4*)(x + (size_t)(t0 + row) * DD + kb + c4 * 4);
            float e[4] = {v.x, v.y, v.z, v.w};
            bf16x4s s1, s2, s3;
#pragma unroll
            for (int q = 0; q < 4; ++q) {
                short h1 = f2bf(e[q]); float r1 = e[q] - bf2f(h1);
                short h2 = f2bf(r1);   float r2 = r1 - bf2f(h2);
                short h3 = f2bf(r2);
                s1[q] = h1; s2[q] = h2; s3[q] = h3;
            }
            int a = row * PW + c4 * 4;
            *(bf16x4s*)&Ax[0][a] = s1; *(bf16x4s*)&Ax[1][a] = s2; *(bf16x4s*)&Ax[2][a] = s3;
        }
        // W tile 256x32 -> 3-way split
#pragma unroll
        for (int j = 0; j < 8; ++j) {
            int idx = j * 256 + tid, row = idx >> 3, c4 = idx & 7;
            float4 v = *(const float4*)(W + (size_t)row * DD + kb + c4 * 4);
            float e[4] = {v.x, v.y, v.z, v.w};
            bf16x4s s1, s2, s3;
#pragma unroll
            for (int q = 0; q < 4; ++q) {
                short h1 = f2bf(e[q]); float r1 = e[q] - bf2f(h1);
                short h2 = f2bf(r1);   float r2 = r1 - bf2f(h2);
                short h3 = f2bf(r2);
                s1[q] = h1; s2[q] = h2; s3[q] = h3;
            }
            int a = row * PW + c4 * 4;
            *(bf16x4s*)&Bw[0][a] = s1; *(bf16x4s*)&Bw[1][a] = s2; *(bf16x4s*)&Bw[2][a] = s3;
        }
        __syncthreads();
#pragma unroll
        for (int ks = 0; ks < 2; ++ks) {
            int ao = (wt + l31) * PW + ks * 16 + h * 8;
            bf16x8 a1 = *(bf16x8*)&Ax[0][ao];
            bf16x8 a2 = *(bf16x8*)&Ax[1][ao];
            bf16x8 a3 = *(bf16x8*)&Ax[2][ao];
#pragma unroll
            for (int cb = 0; cb < 4; ++cb) {
                int bo = (wc + cb * 32 + l31) * PW + ks * 16 + h * 8;
                bf16x8 b1 = *(bf16x8*)&Bw[0][bo];
                bf16x8 b2 = *(bf16x8*)&Bw[1][bo];
                bf16x8 b3 = *(bf16x8*)&Bw[2][bo];
                // small terms first for accumulation accuracy
                acc[cb] = __builtin_amdgcn_mfma_f32_32x32x16_bf16(a1, b3, acc[cb], 0, 0, 0);
                acc[cb] = __builtin_amdgcn_mfma_f32_32x32x16_bf16(a2, b2, acc[cb], 0, 0, 0);
                acc[cb] = __builtin_amdgcn_mfma_f32_32x32x16_bf16(a3, b1, acc[cb], 0, 0, 0);
                acc[cb] = __builtin_amdgcn_mfma_f32_32x32x16_bf16(a1, b2, acc[cb], 0, 0, 0);
                acc[cb] = __builtin_amdgcn_mfma_f32_32x32x16_bf16(a2, b1, acc[cb], 0, 0, 0);
                acc[cb] = __builtin_amdgcn_mfma_f32_32x32x16_bf16(a1, b1, acc[cb], 0, 0, 0);
            }
        }
    }
    // epilogue: C/D layout col=lane&31, row=(r&3)+8*(r>>2)+4*(lane>>5)
#pragma unroll
    for (int cb = 0; cb < 4; ++cb) {
        int col = wc + cb * 32 + l31;
        float bc = bias[col];
#pragma unroll
        for (int r = 0; r < 16; ++r) {
            int row = (r & 3) + 8 * (r >> 2) + 4 * h;
            z[(size_t)(t0 + wt + row) * DD + col] = acc[cb][r] + bc;
        }
    }
}

// ---------------------------------------------------------------------------
// bf16 MFMA screening (EXACT round-3 version, harness-proven incl. replays).
#define SW 264   // A_s row stride (bf16 elems)
#define BW 40    // B_s row stride (bf16 elems)

__launch_bounds__(256, 2)
__global__ void k_screen(const float* __restrict__ z, const float* __restrict__ emb,
                         const float* __restrict__ ee_g, float* __restrict__ out_idx) {
    __shared__ __align__(16) short A_s[64 * SW];
    __shared__ __align__(16) short B_s[128 * BW];
    __shared__ float ee_s[1024];
    __shared__ float zzs[64];
    __shared__ float r_bv[64]; __shared__ int r_bi[64]; __shared__ float r_sv[64];

    const int tid = threadIdx.x;
    const int w = tid >> 6, lane = tid & 63;
    const int l31 = lane & 31, h = lane >> 5;
    const int t0 = blockIdx.x * 64;
    const int wr = (w >> 1) * 32, wc = (w & 1) * 64;

#pragma unroll
    for (int i = 0; i < 4; ++i) ee_s[i * 256 + tid] = ee_g[i * 256 + tid];

    // A init: z tile -> bf16 LDS (full K=256 resident) + exact fp32 zz sums
#pragma unroll
    for (int i = 0; i < 16; ++i) {
        int tl = i * 4 + w;
        float4 v = *(const float4*)(z + (size_t)(t0 + tl) * DD + lane * 4);
        float sq = v.x * v.x + v.y * v.y + v.z * v.z + v.w * v.w;
#pragma unroll
        for (int o = 32; o; o >>= 1) sq += __shfl_xor(sq, o);
        if (lane == 0) zzs[tl] = sq;
        bf16x4s hb = {f2bf(v.x), f2bf(v.y), f2bf(v.z), f2bf(v.w)};
        *(bf16x4s*)&A_s[tl * SW + lane * 4] = hb;
    }

    float bestv[16], secv[16]; int besti[16];
#pragma unroll
    for (int r = 0; r < 16; ++r) { bestv[r] = 1e30f; secv[r] = 1e30f; besti[r] = 0; }

    float4 pre[4];
    {
#pragma unroll
        for (int r = 0; r < 4; ++r) {
            int f = r * 256 + tid, n_loc = f >> 3, c = f & 7;
            pre[r] = *(const float4*)(emb + (size_t)n_loc * DD + c * 4);
        }
    }
    __syncthreads();   // A_s, zzs, ee_s ready

    for (int nc = 0; nc < 8; ++nc) {
        f32x16 acc0, acc1;
#pragma unroll
        for (int r = 0; r < 16; ++r) { acc0[r] = 0.f; acc1[r] = 0.f; }

        for (int kbi = 0; kbi < 8; ++kbi) {
            __syncthreads();
#pragma unroll
            for (int r = 0; r < 4; ++r) {       // write staged B tile
                int f = r * 256 + tid, n_loc = f >> 3, c = f & 7;
                float4 v = pre[r];
                bf16x4s hb = {f2bf(v.x), f2bf(v.y), f2bf(v.z), f2bf(v.w)};
                *(bf16x4s*)&B_s[n_loc * BW + c * 4] = hb;
            }
            __syncthreads();
            {   // prefetch next tile
                int rr = nc * 8 + kbi; int nrr = rr < 63 ? rr + 1 : 63;
                int nnc = nrr >> 3, nkbi = nrr & 7;
#pragma unroll
                for (int r = 0; r < 4; ++r) {
                    int f = r * 256 + tid, n_loc = f >> 3, c = f & 7;
                    pre[r] = *(const float4*)(emb + (size_t)(nnc * 128 + n_loc) * DD + nkbi * 32 + c * 4);
                }
            }
#pragma unroll
            for (int ks = 0; ks < 2; ++ks) {
                bf16x8 a  = *(bf16x8*)&A_s[(wr + l31) * SW + kbi * 32 + ks * 16 + h * 8];
                bf16x8 b0 = *(bf16x8*)&B_s[(wc + l31) * BW + ks * 16 + h * 8];
                bf16x8 b1 = *(bf16x8*)&B_s[(wc + 32 + l31) * BW + ks * 16 + h * 8];
                acc0 = __builtin_amdgcn_mfma_f32_32x32x16_bf16(a, b0, acc0, 0, 0, 0);
                acc1 = __builtin_amdgcn_mfma_f32_32x32x16_bf16(a, b1, acc1, 0, 0, 0);
            }
        }
        // fold: s = fl(fl(zz+ee) - 2*dot), track top-2 values + best index
#pragma unroll
        for (int j = 0; j < 2; ++j) {
            int n = nc * 128 + wc + j * 32 + l31;
            float en = ee_s[n];
#pragma unroll
            for (int r = 0; r < 16; ++r) {
                int row = (r & 3) + 8 * (r >> 2) + 4 * h;
                float u = zzs[wr + row] + en;
                float d = (j == 0) ? acc0[r] : acc1[r];
                float s = fmaf(-2.f, d, u);
                if (s < bestv[r])      { secv[r] = bestv[r]; bestv[r] = s; besti[r] = n; }
                else if (s < secv[r])  { secv[r] = s; }
            }
        }
    }

    // cross-lane reduce within each 32-lane half (cols)
#pragma unroll
    for (int o = 1; o < 32; o <<= 1) {
#pragma unroll
        for (int r = 0; r < 16; ++r) {
            float ov = __shfl_xor(bestv[r], o);
            int   oi = __shfl_xor(besti[r], o);
            float os = __shfl_xor(secv[r], o);
            float mx = fmaxf(bestv[r], ov);
            secv[r] = fminf(fminf(secv[r], os), mx);
            if (ov < bestv[r] || (ov == bestv[r] && oi < besti[r])) { bestv[r] = ov; besti[r] = oi; }
        }
    }
    // combine the two col-parity waves per row block via LDS
    if ((w & 1) == 0 && l31 == 0) {
#pragma unroll
        for (int r = 0; r < 16; ++r) {
            int tr = wr + (r & 3) + 8 * (r >> 2) + 4 * h;
            r_bv[tr] = bestv[r]; r_bi[tr] = besti[r]; r_sv[tr] = secv[r];
        }
    }
    __syncthreads();
    if ((w & 1) == 1 && l31 == 0) {
#pragma unroll
        for (int r = 0; r < 16; ++r) {
            int tr = wr + (r & 3) + 8 * (r >> 2) + 4 * h;
            float lv = r_bv[tr]; int li = r_bi[tr]; float ls = r_sv[tr];
            float mx = fmaxf(lv, bestv[r]);
            float ns = fminf(fminf(ls, secv[r]), mx);
            float nv; int ni;
            if (bestv[r] < lv || (bestv[r] == lv && besti[r] < li)) { nv = bestv[r]; ni = besti[r]; }
            else { nv = lv; ni = li; }
            r_bv[tr] = nv; r_bi[tr] = ni; r_sv[tr] = ns;
        }
    }
    __syncthreads();
    if (tid < 64) {
        float bv = r_bv[tid], sv = r_sv[tid];
        int bi = r_bi[tid];
        float flag = ((sv - bv) < B_S) ? 4096.0f : 0.0f;
        out_idx[t0 + tid] = (float)bi + flag;
    }
}

// ---------------------------------------------------------------------------
// Exact fp32 re-argmin for flagged tokens. Deterministic ballot-built list,
// batches of 8 z-rows in LDS (zero-padded), 4 codes/thread, float4 broadcast.
__launch_bounds__(256, 2)
__global__ void k_rescore(const float* __restrict__ z, const float* __restrict__ emb,
                          const float* __restrict__ ee_g, float* __restrict__ out_idx) {
    __shared__ float zrows[8][260];
    __shared__ float zz8[8];
    __shared__ int   list[64];
    __shared__ int   nflag_s;
    __shared__ float rv_s[8][4]; __shared__ int ri_s[8][4];
    const int tid = threadIdx.x;
    const int w = tid >> 6, lane = tid & 63;
    const int t0 = blockIdx.x * 64;

    if (tid == 0) nflag_s = 0;
    __syncthreads();
    if (tid < 64) {    // wave 0 only: deterministic flag list via ballot
        float v = out_idx[t0 + tid];
        bool fl = (v >= 4096.0f);
        unsigned long long m = __ballot(fl);
        if (fl) {
            int rank = __popcll(m & ((1ull << tid) - 1ull));
            list[rank] = tid;
        }
        if (tid == 0) nflag_s = (int)__popcll(m);
    }
    __syncthreads();
    const int nf = nflag_s;

    for (int base = 0; base < nf; base += 8) {
        const int nt = min(8, nf - base);
        // stage z rows (zero-pad unused rows: no stale-LDS reads)
#pragma unroll
        for (int q = 0; q < 8; ++q) {
            if (q < nt) {
                int t = t0 + list[base + q];
                zrows[q][tid] = z[(size_t)t * DD + tid];
            } else {
                zrows[q][tid] = 0.f;
            }
        }
        __syncthreads();
        // zz per staged row (wave w handles rows w, w+4)
        for (int q = w; q < 8; q += 4) {
            float s = 0.f;
#pragma unroll
            for (int k = 0; k < 4; ++k) { float vv = zrows[q][lane + 64 * k]; s += vv * vv; }
#pragma unroll
            for (int o = 32; o; o >>= 1) s += __shfl_xor(s, o);
            if (lane == 0) zz8[q] = s;
        }
        __syncthreads();

        float bv[8]; int bi[8];
#pragma unroll
        for (int q = 0; q < 8; ++q) { bv[q] = 1e30f; bi[q] = 0; }
        for (int c = 0; c < 4; ++c) {
            int n = c * 256 + tid;
            float en = ee_g[n];
            float d[8];
#pragma unroll
            for (int q = 0; q < 8; ++q) d[q] = 0.f;
            const float4* er = (const float4*)(emb + (size_t)n * DD);
#pragma unroll 4
            for (int k = 0; k < 64; ++k) {
                float4 e = er[k];
#pragma unroll
                for (int q = 0; q < 8; ++q) {
                    float4 zq = *(const float4*)&zrows[q][k * 4];
                    d[q] = fmaf(e.x, zq.x, d[q]); d[q] = fmaf(e.y, zq.y, d[q]);
                    d[q] = fmaf(e.z, zq.z, d[q]); d[q] = fmaf(e.w, zq.w, d[q]);
                }
            }
#pragma unroll
            for (int q = 0; q < 8; ++q) {
                float u = zz8[q] + en;           // fl(zz+ee[n])
                float s = fmaf(-2.f, d[q], u);   // fl(u - 2*dot)
                if (s < bv[q]) { bv[q] = s; bi[q] = n; }   // ascending n/thread
            }
        }
        // per-token block reduce: lexicographic (value, index) first-min
        for (int q = 0; q < nt; ++q) {
            float v = bv[q]; int i = bi[q];
#pragma unroll
            for (int o = 1; o < 64; o <<= 1) {
                float ov = __shfl_xor(v, o); int oi = __shfl_xor(i, o);
                if (ov < v || (ov == v && oi < i)) { v = ov; i = oi; }
            }
            if (lane == 0) { rv_s[q][w] = v; ri_s[q][w] = i; }
        }
        __syncthreads();
        if (tid < nt) {
            float fv = rv_s[tid][0]; int fi = ri_s[tid][0];
#pragma unroll
            for (int ww = 1; ww < 4; ++ww) {
                if (rv_s[tid][ww] < fv || (rv_s[tid][ww] == fv && ri_s[tid][ww] < fi)) {
                    fv = rv_s[tid][ww]; fi = ri_s[tid][ww];
                }
            }
            out_idx[t0 + list[base + tid]] = (float)fi;
        }
        __syncthreads();
    }
}

// ---------------------------------------------------------------------------
__global__ void k_gather(float* __restrict__ zq, const float* __restrict__ emb,
                         const float* __restrict__ out_idx, float* __restrict__ partial) {
    __shared__ float red[4];
    const int tid = threadIdx.x;
    const int t0 = blockIdx.x * 128;
    const int tl = tid >> 1, part = tid & 1;
    int widx = (int)out_idx[t0 + tl];
    widx = min(max(widx, 0), KK - 1);
    const float* erow = emb + (size_t)widx * DD;
    float* qrow = zq + (size_t)(t0 + tl) * DD;
    float lsum = 0.f;
#pragma unroll
    for (int k = 0; k < 32; ++k) {
        int f = part + 2 * k;
        float4 e  = *(const float4*)(erow + f * 4);
        float4 zv = *(const float4*)(qrow + f * 4);
        float dx = e.x - zv.x, dy = e.y - zv.y, dz = e.z - zv.z, dw = e.w - zv.w;
        lsum += dx * dx + dy * dy + dz * dz + dw * dw;
        *(float4*)(qrow + f * 4) = e;
    }
#pragma unroll
    for (int off = 32; off; off >>= 1) lsum += __shfl_down(lsum, off);
    if ((tid & 63) == 0) red[tid >> 6] = lsum;
    __syncthreads();
    if (tid == 0) partial[blockIdx.x] = red[0] + red[1] + red[2] + red[3];
}

// ---------------------------------------------------------------------------
__global__ void k_loss(const float* __restrict__ partial, float* __restrict__ out_loss) {
    __shared__ float red[4];
    int tid = threadIdx.x;
    float s = partial[tid];
#pragma unroll
    for (int off = 32; off; off >>= 1) s += __shfl_down(s, off);
    if ((tid & 63) == 0) red[tid >> 6] = s;
    __syncthreads();
    if (tid == 0)
        out_loss[0] = (red[0] + red[1] + red[2] + red[3]) * (1.25f / 8388608.0f);
}

// ---------------------------------------------------------------------------
extern "C" void kernel_launch(void* const* d_in, const int* in_sizes, int n_in,
                              void* d_out, int out_size, void* d_ws, size_t ws_size,
                              hipStream_t stream) {
    const float* x   = (const float*)d_in[0];
    const float* W   = (const float*)d_in[1];
    const float* b   = (const float*)d_in[2];
    const float* emb = (const float*)d_in[3];

    float* out   = (float*)d_out;
    float* quant = out;                          // holds z, then quant
    float* oidx  = out + (size_t)TT * DD;
    float* oloss = oidx + TT;

    float* ee      = (float*)d_ws;               // 1024 f
    float* partial = ee + KK;                    // 256 f

    k_ee     <<<KK / 256, 256, 0, stream>>>(emb, ee);
    k_proj   <<<TT / 64,  256, 0, stream>>>(x, W, b, quant);
    k_screen <<<TT / 64,  256, 0, stream>>>(quant, emb, ee, oidx);
    k_rescore<<<TT / 64,  256, 0, stream>>>(quant, emb, ee, oidx);
    k_gather <<<TT / 128, 256, 0, stream>>>(quant, emb, oidx, partial);
    k_loss   <<<1,        256, 0, stream>>>(partial, oloss);
}